// Round 7
// baseline (650.953 us; speedup 1.0000x reference)
//
#include <hip/hip_runtime.h>
#include <math.h>

#define HIDC 128
#define OUTC 40
#define BN_EPS 1e-5f
#define MAXBUK 784          // >= ceil(100000/128)
#define TILE 8192
#define BCAP 4096           // per-bucket LDS sort capacity (avg bucket ~2045)

typedef __attribute__((ext_vector_type(8))) short bf16x8;
typedef __attribute__((ext_vector_type(4))) float f32x4;

// ---------------- bf16 helpers ----------------
__device__ __forceinline__ unsigned short f2bf(float f) {
  union { float f; unsigned u; } v; v.f = f;
  unsigned r = v.u + 0x7fff + ((v.u >> 16) & 1);   // RNE
  return (unsigned short)(r >> 16);
}
__device__ __forceinline__ float bf2f(unsigned short h) {
  union { unsigned u; float f; } v; v.u = ((unsigned)h) << 16;
  return v.f;
}

// ---------------- bucket-CSR build ----------------
// bucket b = dst >> 7 (128 nodes/bucket). pair = src | (dst&127)<<17  (src < 2^17).

__global__ __launch_bounds__(256) void bin_hist(const int* __restrict__ dst,
                                                int* __restrict__ bucketCount,
                                                int E, int NBUK) {
  __shared__ int h[MAXBUK];
  int t = threadIdx.x;
  for (int i = t; i < NBUK; i += 256) h[i] = 0;
  __syncthreads();
  int idx = blockIdx.x * 256 + t;
  int stride = gridDim.x * 256;
  for (int e = idx; e < E; e += stride) atomicAdd(&h[dst[e] >> 7], 1);
  __syncthreads();
  for (int i = t; i < NBUK; i += 256) if (h[i]) atomicAdd(&bucketCount[i], h[i]);
}

__global__ __launch_bounds__(512) void scan_buckets(const int* __restrict__ bucketCount,
                                                    int* __restrict__ bucketStart,
                                                    int* __restrict__ cursor,
                                                    int NBUK, int E) {
  __shared__ int ssc[512];
  int t = threadIdx.x;
  int c0 = (2 * t < NBUK) ? bucketCount[2 * t] : 0;
  int c1 = (2 * t + 1 < NBUK) ? bucketCount[2 * t + 1] : 0;
  ssc[t] = c0 + c1;
  __syncthreads();
  for (int off = 1; off < 512; off <<= 1) {
    int v = (t >= off) ? ssc[t - off] : 0;
    __syncthreads();
    ssc[t] += v;
    __syncthreads();
  }
  int base = ssc[t] - (c0 + c1);   // exclusive
  if (2 * t < NBUK)     { bucketStart[2 * t] = base;          cursor[2 * t] = base; }
  if (2 * t + 1 < NBUK) { bucketStart[2 * t + 1] = base + c0; cursor[2 * t + 1] = base + c0; }
  if (t == 511) bucketStart[NBUK] = E;
}

__global__ __launch_bounds__(512) void bin_scatter(const int* __restrict__ src,
                                                   const int* __restrict__ dst,
                                                   int* __restrict__ cursor,
                                                   unsigned* __restrict__ pairs,
                                                   int E, int NBUK) {
  __shared__ unsigned ord[TILE];
  __shared__ int hist[MAXBUK], scanS[MAXBUK], gbase[MAXBUK], rank[MAXBUK];
  __shared__ int ssc[512];
  int t = threadIdx.x;
  int tb = blockIdx.x * TILE;
  int nT = min(TILE, E - tb);
  for (int i = t; i < NBUK; i += 512) { hist[i] = 0; rank[i] = 0; }
  __syncthreads();
  for (int i = t; i < nT; i += 512) atomicAdd(&hist[dst[tb + i] >> 7], 1);
  __syncthreads();
  int c0 = (2 * t < NBUK) ? hist[2 * t] : 0;
  int c1 = (2 * t + 1 < NBUK) ? hist[2 * t + 1] : 0;
  ssc[t] = c0 + c1;
  __syncthreads();
  for (int off = 1; off < 512; off <<= 1) {
    int v = (t >= off) ? ssc[t - off] : 0;
    __syncthreads();
    ssc[t] += v;
    __syncthreads();
  }
  int bse = ssc[t] - (c0 + c1);
  if (2 * t < NBUK) scanS[2 * t] = bse;
  if (2 * t + 1 < NBUK) scanS[2 * t + 1] = bse + c0;
  __syncthreads();
  for (int i = t; i < NBUK; i += 512) {
    int c = hist[i];
    if (c) gbase[i] = atomicAdd(&cursor[i], c);
  }
  __syncthreads();
  for (int i = t; i < nT; i += 512) {
    int d = dst[tb + i], s = src[tb + i];
    int b = d >> 7;
    int pos = scanS[b] + atomicAdd(&rank[b], 1);
    ord[pos] = (unsigned)s | ((unsigned)(d & 127) << 17);
  }
  __syncthreads();
  // coalesced flush: wave per bucket round-robin
  int wid = t >> 6, lane = t & 63;
  for (int b = wid; b < NBUK; b += 8) {
    int c = hist[b];
    if (!c) continue;
    int gb = gbase[b], sb = scanS[b];
    for (int j = lane; j < c; j += 64) pairs[gb + j] = ord[sb + j];
  }
}

// per-bucket counting sort -> per-node CSR (coalesced writes) + counts/rowStart/dis
__global__ __launch_bounds__(256) void csr_from_pairs(const unsigned* __restrict__ pairs,
                                                      const int* __restrict__ bucketStart,
                                                      int* __restrict__ csrSrc,
                                                      int* __restrict__ counts,
                                                      int* __restrict__ rowStart,
                                                      float* __restrict__ dis, int N) {
  __shared__ int hist[128], excl[128], rank[128];
  __shared__ int ordS[BCAP];
  int b = blockIdx.x, t = threadIdx.x;
  int base = b << 7;
  int e0 = bucketStart[b], e1 = bucketStart[b + 1];
  int cnt = e1 - e0;
  if (t < 128) { hist[t] = 0; rank[t] = 0; }
  __syncthreads();
  for (int e = e0 + t; e < e1; e += 256) atomicAdd(&hist[pairs[e] >> 17], 1);
  __syncthreads();
  if (t < 128) excl[t] = hist[t];
  __syncthreads();
  for (int off = 1; off < 128; off <<= 1) {
    int v = (t < 128 && t >= off) ? excl[t - off] : 0;
    __syncthreads();
    if (t < 128) excl[t] += v;
    __syncthreads();
  }
  if (t < 128) excl[t] -= hist[t];   // exclusive
  __syncthreads();
  if (t < 128 && base + t < N) {
    int c = hist[t];
    counts[base + t] = c;
    rowStart[base + t] = e0 + excl[t];
    dis[base + t] = rsqrtf((float)(c + 1));
  }
  if (cnt <= BCAP) {
    for (int e = e0 + t; e < e1; e += 256) {
      unsigned p = pairs[e];
      int dl = p >> 17;
      int pos = excl[dl] + atomicAdd(&rank[dl], 1);
      ordS[pos] = (int)(p & 0x1FFFF);
    }
    __syncthreads();
    for (int j = t; j < cnt; j += 256) csrSrc[e0 + j] = ordS[j];
  } else {  // fallback
    for (int e = e0 + t; e < e1; e += 256) {
      unsigned p = pairs[e];
      int dl = p >> 17;
      int pos = excl[dl] + atomicAdd(&rank[dl], 1);
      csrSrc[e0 + pos] = (int)(p & 0x1FFFF);
    }
  }
}

// ---------------- W prep: fp32 -> W^T bf16, XOR-swizzled in k ----------------
// element (n,k) stored at n*128 + (k ^ ((n&15)<<3)) -> gemm stages LINEARLY into LDS
__global__ __launch_bounds__(256) void wprep(const float* __restrict__ W1,
                                             const float* __restrict__ W2,
                                             const float* __restrict__ W3,
                                             unsigned short* __restrict__ W1s,
                                             unsigned short* __restrict__ W2s,
                                             unsigned short* __restrict__ W3s) {
  int t = threadIdx.x;
  if (blockIdx.x < 2) {
    const float* W = blockIdx.x ? W2 : W1;
    unsigned short* Ws = blockIdx.x ? W2s : W1s;
    for (int idx = t; idx < 128 * 128; idx += 256) {
      int n = idx >> 7, k = idx & 127;
      Ws[n * 128 + (k ^ ((n & 15) << 3))] = f2bf(W[k * 128 + n]);
    }
  } else {   // W3: [128][40] -> [48][128] padded
    for (int idx = t; idx < 48 * 128; idx += 256) {
      int n = idx >> 7, k = idx & 127;
      float v = (n < OUTC) ? W3[k * OUTC + n] : 0.f;
      W3s[n * 128 + (k ^ ((n & 15) << 3))] = f2bf(v);
    }
  }
}

// ---------------- MFMA GEMM: [N,128] x [128,128] -> bf16 ----------------
// MODE 0: A fp32, no BN (layer 1). MODE 1: A bf16, fused BN+ReLU (layer 2).
template<int MODE>
__global__ __launch_bounds__(256) void gemm128m(const void* __restrict__ Ain,
                                                const unsigned short* __restrict__ Wsz,
                                                const float* __restrict__ bnsc,
                                                const float* __restrict__ bnsh,
                                                unsigned short* __restrict__ Cbf, int N) {
  __shared__ unsigned short Asw[64 * 128];    // 16 KB, XOR-swizzled
  __shared__ unsigned short Wsw[128 * 128];   // 32 KB, pre-swizzled (linear copy)
  __shared__ float scs[128], shs[128];
  int t = threadIdx.x;
  int rowBase = blockIdx.x * 64;

  if (MODE == 1 && t < 128) { scs[t] = bnsc[t]; shs[t] = bnsh[t]; }
  __syncthreads();

  // stage W: linear coalesced copy (swizzle pre-applied in global)
  {
    const float4* wg = (const float4*)Wsz;
    float4* wl = (float4*)Wsw;
    #pragma unroll
    for (int i = 0; i < 8; ++i) wl[t + 256 * i] = wg[t + 256 * i];
  }
  // stage A, swizzled ds_write_b128
  {
    int r = t >> 2;                // 0..63
    int kc = (t & 3) << 5;         // 0,32,64,96
    int gr = rowBase + r;
    #pragma unroll
    for (int j = 0; j < 4; ++j) {
      int k0 = kc + j * 8;
      float v[8];
      if (gr < N) {
        if (MODE == 0) {
          const float* arow = (const float*)Ain + (size_t)gr * 128 + k0;
          float4 a = *(const float4*)arow;
          float4 b = *(const float4*)(arow + 4);
          v[0] = a.x; v[1] = a.y; v[2] = a.z; v[3] = a.w;
          v[4] = b.x; v[5] = b.y; v[6] = b.z; v[7] = b.w;
        } else {
          const unsigned short* arow = (const unsigned short*)Ain + (size_t)gr * 128 + k0;
          bf16x8 raw = *(const bf16x8*)arow;
          #pragma unroll
          for (int i = 0; i < 8; ++i)
            v[i] = fmaxf(bf2f((unsigned short)raw[i]) * scs[k0 + i] + shs[k0 + i], 0.f);
        }
      } else {
        #pragma unroll
        for (int i = 0; i < 8; ++i) v[i] = 0.f;
      }
      bf16x8 sv;
      #pragma unroll
      for (int i = 0; i < 8; ++i) sv[i] = (short)f2bf(v[i]);
      *(bf16x8*)&Asw[r * 128 + (k0 ^ ((r & 15) << 3))] = sv;
    }
  }
  __syncthreads();

  int w = t >> 6, l = t & 63;
  int lr = l & 15;
  int lk = (l >> 4) << 3;
  f32x4 acc[8];
  #pragma unroll
  for (int nt = 0; nt < 8; ++nt) acc[nt] = (f32x4){0.f, 0.f, 0.f, 0.f};

  #pragma unroll
  for (int kt = 0; kt < 128; kt += 32) {
    int kx = (kt + lk) ^ (lr << 3);
    bf16x8 af = *(const bf16x8*)&Asw[(w * 16 + lr) * 128 + kx];
    #pragma unroll
    for (int nt = 0; nt < 8; ++nt) {
      bf16x8 bfv = *(const bf16x8*)&Wsw[(nt * 16 + lr) * 128 + kx];
      acc[nt] = __builtin_amdgcn_mfma_f32_16x16x32_bf16(af, bfv, acc[nt], 0, 0, 0);
    }
  }

  // D[m][n]: m = (l>>4)*4 + reg, n = nt*16 + lr
  int m0 = rowBase + w * 16 + ((l >> 4) << 2);
  #pragma unroll
  for (int i = 0; i < 4; ++i) {
    int gm = m0 + i;
    if (gm < N) {
      unsigned short* cr = Cbf + (size_t)gm * 128 + lr;
      #pragma unroll
      for (int nt = 0; nt < 8; ++nt) cr[nt * 16] = f2bf(acc[nt][i]);
    }
  }
}

// ---------------- MFMA GEMM: [N,128] x [128,40] with fused BN+ReLU; writes fp32 h ----------------
__global__ __launch_bounds__(256) void gemm40m(const unsigned short* __restrict__ Apre,
                                               const unsigned short* __restrict__ W3sz,
                                               const float* __restrict__ bnsc,
                                               const float* __restrict__ bnsh,
                                               float* __restrict__ hOut,
                                               unsigned short* __restrict__ Cbf, int N) {
  __shared__ unsigned short Asw[64 * 128];   // 16 KB
  __shared__ unsigned short Wsw[48 * 128];   // 12 KB
  __shared__ float scs[128], shs[128];
  int t = threadIdx.x;
  int rowBase = blockIdx.x * 64;
  if (t < 128) { scs[t] = bnsc[t]; shs[t] = bnsh[t]; }
  __syncthreads();
  // stage W3 (48*128*2 B = 768 float4)
  {
    const float4* wg = (const float4*)W3sz;
    float4* wl = (float4*)Wsw;
    #pragma unroll
    for (int i = 0; i < 3; ++i) wl[t + 256 * i] = wg[t + 256 * i];
  }
  // stage A with BN+ReLU; write post-BN h (fp32) — this IS output 2
  {
    int r = t >> 2;
    int kc = (t & 3) << 5;
    int gr = rowBase + r;
    const unsigned short* arow = Apre + (size_t)gr * 128 + kc;
    float* hrow = hOut + (size_t)gr * 128 + kc;
    #pragma unroll
    for (int j = 0; j < 4; ++j) {
      int k0 = kc + j * 8;
      float v[8];
      if (gr < N) {
        bf16x8 raw = *(const bf16x8*)(arow + j * 8);
        #pragma unroll
        for (int i = 0; i < 8; ++i)
          v[i] = fmaxf(bf2f((unsigned short)raw[i]) * scs[k0 + i] + shs[k0 + i], 0.f);
        float4 h0 = make_float4(v[0], v[1], v[2], v[3]);
        float4 h1 = make_float4(v[4], v[5], v[6], v[7]);
        *(float4*)(hrow + j * 8) = h0;
        *(float4*)(hrow + j * 8 + 4) = h1;
      } else {
        #pragma unroll
        for (int i = 0; i < 8; ++i) v[i] = 0.f;
      }
      bf16x8 sv;
      #pragma unroll
      for (int i = 0; i < 8; ++i) sv[i] = (short)f2bf(v[i]);
      *(bf16x8*)&Asw[r * 128 + (k0 ^ ((r & 15) << 3))] = sv;
    }
  }
  __syncthreads();
  int w = t >> 6, l = t & 63;
  int lr = l & 15, lk = (l >> 4) << 3;
  f32x4 acc[3];
  #pragma unroll
  for (int nt = 0; nt < 3; ++nt) acc[nt] = (f32x4){0.f, 0.f, 0.f, 0.f};
  #pragma unroll
  for (int kt = 0; kt < 128; kt += 32) {
    int kx = (kt + lk) ^ (lr << 3);
    bf16x8 af = *(const bf16x8*)&Asw[(w * 16 + lr) * 128 + kx];
    #pragma unroll
    for (int nt = 0; nt < 3; ++nt) {
      bf16x8 bfv = *(const bf16x8*)&Wsw[(nt * 16 + lr) * 128 + kx];
      acc[nt] = __builtin_amdgcn_mfma_f32_16x16x32_bf16(af, bfv, acc[nt], 0, 0, 0);
    }
  }
  int m0 = rowBase + w * 16 + ((l >> 4) << 2);
  #pragma unroll
  for (int i = 0; i < 4; ++i) {
    int gm = m0 + i;
    if (gm < N) {
      unsigned short* cr = Cbf + (size_t)gm * OUTC;
      #pragma unroll
      for (int nt = 0; nt < 3; ++nt) {
        int col = nt * 16 + lr;
        if (col < OUTC) cr[col] = f2bf(acc[nt][i]);
      }
    }
  }
}

// ---------------- aggregation (128 ch, bf16 src): 32 threads/node, bf16 out ----------------
__global__ __launch_bounds__(256) void agg128(const unsigned short* __restrict__ hb,
                                              const float* __restrict__ dis,
                                              const int* __restrict__ rowStart,
                                              const int* __restrict__ counts,
                                              const int* __restrict__ csrSrc,
                                              const float* __restrict__ bias,
                                              unsigned short* __restrict__ outB, int N) {
  int g = threadIdx.x >> 5;
  int q = threadIdx.x & 31;          // owns channels 4q..4q+3
  int i = blockIdx.x * 8 + g;
  if (i >= N) return;
  const ushort4* base = (const ushort4*)hb;  // row = 32 ushort4
  float di = dis[i];
  float wself = di * di;
  ushort4 sv = base[(size_t)i * 32 + q];
  float4 acc;
  acc.x = bf2f(sv.x) * wself; acc.y = bf2f(sv.y) * wself;
  acc.z = bf2f(sv.z) * wself; acc.w = bf2f(sv.w) * wself;
  int s0 = rowStart[i];
  int cnt = counts[i];
  int e = 0;
  for (; e + 3 < cnt; e += 4) {
    int sA = csrSrc[s0 + e],     sB = csrSrc[s0 + e + 1];
    int sC = csrSrc[s0 + e + 2], sD = csrSrc[s0 + e + 3];
    float wA = dis[sA] * di, wB = dis[sB] * di;
    float wC = dis[sC] * di, wD = dis[sD] * di;
    ushort4 vA = base[(size_t)sA * 32 + q];
    ushort4 vB = base[(size_t)sB * 32 + q];
    ushort4 vC = base[(size_t)sC * 32 + q];
    ushort4 vD = base[(size_t)sD * 32 + q];
    acc.x += bf2f(vA.x) * wA; acc.y += bf2f(vA.y) * wA;
    acc.z += bf2f(vA.z) * wA; acc.w += bf2f(vA.w) * wA;
    acc.x += bf2f(vB.x) * wB; acc.y += bf2f(vB.y) * wB;
    acc.z += bf2f(vB.z) * wB; acc.w += bf2f(vB.w) * wB;
    acc.x += bf2f(vC.x) * wC; acc.y += bf2f(vC.y) * wC;
    acc.z += bf2f(vC.z) * wC; acc.w += bf2f(vC.w) * wC;
    acc.x += bf2f(vD.x) * wD; acc.y += bf2f(vD.y) * wD;
    acc.z += bf2f(vD.z) * wD; acc.w += bf2f(vD.w) * wD;
  }
  for (; e < cnt; ++e) {
    int sA = csrSrc[s0 + e];
    float wA = dis[sA] * di;
    ushort4 vA = base[(size_t)sA * 32 + q];
    acc.x += bf2f(vA.x) * wA; acc.y += bf2f(vA.y) * wA;
    acc.z += bf2f(vA.z) * wA; acc.w += bf2f(vA.w) * wA;
  }
  float4 b = ((const float4*)bias)[q];
  ushort4 o;
  o.x = f2bf(acc.x + b.x); o.y = f2bf(acc.y + b.y);
  o.z = f2bf(acc.z + b.z); o.w = f2bf(acc.w + b.w);
  *(ushort4*)&outB[(size_t)i * 128 + 4 * q] = o;
}

// ---------------- BatchNorm stats from bf16 (bf16x8 reads) ----------------
__global__ __launch_bounds__(256) void bn_stats_bf(const unsigned short* __restrict__ h,
                                                   float* __restrict__ stats, int N) {
  int t = threadIdx.x;
  int q = t & 15;     // channel octet
  int rg = t >> 4;    // 0..15
  float s[8], s2[8];
  #pragma unroll
  for (int k = 0; k < 8; ++k) { s[k] = 0.f; s2[k] = 0.f; }
  for (int r = blockIdx.x * 16 + rg; r < N; r += gridDim.x * 16) {
    bf16x8 v = *(const bf16x8*)&h[(size_t)r * 128 + q * 8];
    #pragma unroll
    for (int k = 0; k < 8; ++k) {
      float f = bf2f((unsigned short)v[k]);
      s[k] += f; s2[k] += f * f;
    }
  }
  __shared__ float sm[256][16];
  #pragma unroll
  for (int k = 0; k < 8; ++k) { sm[t][k] = s[k]; sm[t][8 + k] = s2[k]; }
  __syncthreads();
  if (t < 16) {
    float a[16];
    #pragma unroll
    for (int k = 0; k < 16; ++k) a[k] = 0.f;
    for (int j = 0; j < 16; ++j)
      #pragma unroll
      for (int k = 0; k < 16; ++k) a[k] += sm[t + 16 * j][k];
    #pragma unroll
    for (int k = 0; k < 8; ++k) {
      atomicAdd(&stats[8 * t + k], a[k]);
      atomicAdd(&stats[128 + 8 * t + k], a[8 + k]);
    }
  }
}

__global__ void bn_scale(float* __restrict__ stats, const float* __restrict__ g,
                         const float* __restrict__ be, float invN) {
  int c = threadIdx.x;  // 128 threads
  float mean = stats[c] * invN;
  float var = stats[128 + c] * invN - mean * mean;
  float sc = g[c] * rsqrtf(var + BN_EPS);
  stats[256 + c] = sc;
  stats[384 + c] = be[c] - mean * sc;
}

// ---------------- layer-3 aggregation + bias + softmax (16 lanes/node, bf16 source) ----------------
__global__ __launch_bounds__(256) void agg40_softmax(const unsigned short* __restrict__ hb,
                                                     const float* __restrict__ dis,
                                                     const int* __restrict__ rowStart,
                                                     const int* __restrict__ counts,
                                                     const int* __restrict__ csrSrc,
                                                     const float* __restrict__ b3,
                                                     float* __restrict__ out, int N) {
  int l = threadIdx.x & 15;      // lanes 0..9 active (10*4 = 40 ch)
  int g = threadIdx.x >> 4;      // 16 nodes/block
  int i = blockIdx.x * 16 + g;
  if (i >= N) return;
  bool act = l < 10;
  float di = dis[i];
  float4 acc = make_float4(0.f, 0.f, 0.f, 0.f);
  if (act) {
    ushort4 sv = *(const ushort4*)&hb[(size_t)i * OUTC + l * 4];
    float w = di * di;
    acc.x = bf2f(sv.x) * w; acc.y = bf2f(sv.y) * w;
    acc.z = bf2f(sv.z) * w; acc.w = bf2f(sv.w) * w;
  }
  int s0 = rowStart[i];
  int cnt = counts[i];
  int e = 0;
  for (; e + 1 < cnt; e += 2) {
    int sA = csrSrc[s0 + e], sB = csrSrc[s0 + e + 1];
    float wA = dis[sA] * di, wB = dis[sB] * di;
    if (act) {
      ushort4 vA = *(const ushort4*)&hb[(size_t)sA * OUTC + l * 4];
      ushort4 vB = *(const ushort4*)&hb[(size_t)sB * OUTC + l * 4];
      acc.x += bf2f(vA.x) * wA; acc.y += bf2f(vA.y) * wA;
      acc.z += bf2f(vA.z) * wA; acc.w += bf2f(vA.w) * wA;
      acc.x += bf2f(vB.x) * wB; acc.y += bf2f(vB.y) * wB;
      acc.z += bf2f(vB.z) * wB; acc.w += bf2f(vB.w) * wB;
    }
  }
  if (e < cnt) {
    int sA = csrSrc[s0 + e];
    float wA = dis[sA] * di;
    if (act) {
      ushort4 vA = *(const ushort4*)&hb[(size_t)sA * OUTC + l * 4];
      acc.x += bf2f(vA.x) * wA; acc.y += bf2f(vA.y) * wA;
      acc.z += bf2f(vA.z) * wA; acc.w += bf2f(vA.w) * wA;
    }
  }
  if (act) {
    float4 b = ((const float4*)b3)[l];
    acc.x += b.x; acc.y += b.y; acc.z += b.z; acc.w += b.w;
  }
  float m = act ? fmaxf(fmaxf(acc.x, acc.y), fmaxf(acc.z, acc.w)) : -1e30f;
  #pragma unroll
  for (int off = 8; off; off >>= 1) m = fmaxf(m, __shfl_xor(m, off, 16));
  float4 ex = make_float4(0.f, 0.f, 0.f, 0.f);
  float lsum = 0.f;
  if (act) {
    ex.x = __expf(acc.x - m); ex.y = __expf(acc.y - m);
    ex.z = __expf(acc.z - m); ex.w = __expf(acc.w - m);
    lsum = ex.x + ex.y + ex.z + ex.w;
  }
  #pragma unroll
  for (int off = 8; off; off >>= 1) lsum += __shfl_xor(lsum, off, 16);
  if (act) {
    float inv = 1.0f / lsum;
    float4 o;
    o.x = ex.x * inv; o.y = ex.y * inv; o.z = ex.z * inv; o.w = ex.w * inv;
    *(float4*)&out[(size_t)i * OUTC + l * 4] = o;
  }
}

// ---------------- launcher ----------------
extern "C" void kernel_launch(void* const* d_in, const int* in_sizes, int n_in,
                              void* d_out, int out_size, void* d_ws, size_t ws_size,
                              hipStream_t stream) {
  const float* x   = (const float*)d_in[0];
  const int*   ei  = (const int*)d_in[1];
  const float* W1  = (const float*)d_in[2];
  const float* b1  = (const float*)d_in[3];
  const float* g1  = (const float*)d_in[4];
  const float* be1 = (const float*)d_in[5];
  const float* W2  = (const float*)d_in[6];
  const float* b2  = (const float*)d_in[7];
  const float* g2  = (const float*)d_in[8];
  const float* be2 = (const float*)d_in[9];
  const float* W3  = (const float*)d_in[10];
  const float* b3  = (const float*)d_in[11];

  const int N = in_sizes[0] / HIDC;
  const int E = in_sizes[1] / 2;
  const int NBUK = (N + 127) >> 7;
  const int* srcI = ei;
  const int* dstI = ei + E;

  float* outSoft = (float*)d_out;                       // [N,40]
  float* outH    = (float*)d_out + (size_t)N * OUTC;    // [N,128] final h (written by gemm40m)

  char* ws = (char*)d_ws;
  size_t off = 0;
  auto alloc = [&](size_t bytes) -> char* {
    char* p = ws + off;
    off += (bytes + 255) & ~(size_t)255;
    return p;
  };
  unsigned short* bufAbf  = (unsigned short*)alloc((size_t)N * HIDC * 2);  // gemm out (bf16)
  unsigned short* hPre    = (unsigned short*)alloc((size_t)N * HIDC * 2);  // preBN agg (bf16)
  unsigned short* buf40bf = (unsigned short*)alloc((size_t)N * OUTC * 2);  // gemm40 out (bf16)
  unsigned short* W1sz    = (unsigned short*)alloc(128 * 128 * 2);
  unsigned short* W2sz    = (unsigned short*)alloc(128 * 128 * 2);
  unsigned short* W3sz    = (unsigned short*)alloc(48 * 128 * 2);
  float*    dis         = (float*)alloc((size_t)N * 4);
  float*    stats       = (float*)alloc(1024 * 4);
  int*      bucketCount = (int*)alloc((size_t)MAXBUK * 4);
  int*      bucketStart = (int*)alloc((size_t)(MAXBUK + 1) * 4);
  int*      cursor      = (int*)alloc((size_t)MAXBUK * 4);
  int*      counts      = (int*)alloc((size_t)N * 4);
  int*      rowStart    = (int*)alloc((size_t)N * 4);
  unsigned* pairs       = (unsigned*)alloc((size_t)E * 4);
  int*      csrSrc      = (int*)alloc((size_t)E * 4);
  (void)ws_size; (void)n_in;

  hipMemsetAsync(bucketCount, 0, (size_t)MAXBUK * 4, stream);
  hipMemsetAsync(stats, 0, 1024 * 4, stream);

  // bucket-sorted CSR build (all writes coalesced) + W prep
  wprep<<<3, 256, 0, stream>>>(W1, W2, W3, W1sz, W2sz, W3sz);
  bin_hist<<<512, 256, 0, stream>>>(dstI, bucketCount, E, NBUK);
  scan_buckets<<<1, 512, 0, stream>>>(bucketCount, bucketStart, cursor, NBUK, E);
  bin_scatter<<<(E + TILE - 1) / TILE, 512, 0, stream>>>(srcI, dstI, cursor, pairs, E, NBUK);
  csr_from_pairs<<<NBUK, 256, 0, stream>>>(pairs, bucketStart, csrSrc, counts, rowStart,
                                           dis, N);

  const float invN = 1.0f / (float)N;

  // ---- Layer 1: x -> bufAbf -> hPre (bf16 preBN) ----
  gemm128m<0><<<(N + 63) / 64, 256, 0, stream>>>(x, W1sz, nullptr, nullptr, bufAbf, N);
  agg128<<<(N + 7) / 8, 256, 0, stream>>>(bufAbf, dis, rowStart, counts, csrSrc,
                                          b1, hPre, N);
  bn_stats_bf<<<512, 256, 0, stream>>>(hPre, stats, N);
  bn_scale<<<1, 128, 0, stream>>>(stats, g1, be1, invN);

  // ---- Layer 2: BN1+ReLU fused into gemm A-load (bf16 A) ----
  gemm128m<1><<<(N + 63) / 64, 256, 0, stream>>>(hPre, W2sz, stats + 256, stats + 384,
                                                 bufAbf, N);
  agg128<<<(N + 7) / 8, 256, 0, stream>>>(bufAbf, dis, rowStart, counts, csrSrc,
                                          b2, hPre, N);
  bn_stats_bf<<<512, 256, 0, stream>>>(hPre, stats + 512, N);
  bn_scale<<<1, 128, 0, stream>>>(stats + 512, g2, be2, invN);

  // ---- Layer 3: BN2+ReLU fused into gemm40m (writes fp32 h to outH) ----
  gemm40m<<<(N + 63) / 64, 256, 0, stream>>>(hPre, W3sz, stats + 768, stats + 896,
                                             outH, buf40bf, N);
  agg40_softmax<<<(N + 15) / 16, 256, 0, stream>>>(buf40bf, dis, rowStart, counts,
                                                   csrSrc, b3, outSoft, N);
}

// Round 8
// 485.979 us; speedup vs baseline: 1.3395x; 1.3395x over previous
//
#include <hip/hip_runtime.h>
#include <math.h>

#define HIDC 128
#define OUTC 40
#define BN_EPS 1e-5f
#define MAXBUK 784          // >= ceil(100000/128)
#define TILE 8192
#define BCAP 4096           // per-bucket LDS sort capacity (avg bucket ~2045)
#define STATB 256           // bn partial-reduction blocks

typedef __attribute__((ext_vector_type(8))) short bf16x8;
typedef __attribute__((ext_vector_type(4))) float f32x4;

// ---------------- bf16 helpers ----------------
__device__ __forceinline__ unsigned short f2bf(float f) {
  union { float f; unsigned u; } v; v.f = f;
  unsigned r = v.u + 0x7fff + ((v.u >> 16) & 1);   // RNE
  return (unsigned short)(r >> 16);
}
__device__ __forceinline__ float bf2f(unsigned short h) {
  union { unsigned u; float f; } v; v.u = ((unsigned)h) << 16;
  return v.f;
}

// ---------------- bucket-CSR build ----------------
// bucket b = dst >> 7 (128 nodes/bucket). pair = src | (dst&127)<<17  (src < 2^17).

__global__ __launch_bounds__(256) void bin_hist(const int* __restrict__ dst,
                                                int* __restrict__ bucketCount,
                                                int E, int NBUK) {
  __shared__ int h[MAXBUK];
  int t = threadIdx.x;
  for (int i = t; i < NBUK; i += 256) h[i] = 0;
  __syncthreads();
  int idx = blockIdx.x * 256 + t;
  int stride = gridDim.x * 256;
  for (int e = idx; e < E; e += stride) atomicAdd(&h[dst[e] >> 7], 1);
  __syncthreads();
  for (int i = t; i < NBUK; i += 256) if (h[i]) atomicAdd(&bucketCount[i], h[i]);
}

__global__ __launch_bounds__(512) void scan_buckets(const int* __restrict__ bucketCount,
                                                    int* __restrict__ bucketStart,
                                                    int* __restrict__ cursor,
                                                    int NBUK, int E) {
  __shared__ int ssc[512];
  int t = threadIdx.x;
  int c0 = (2 * t < NBUK) ? bucketCount[2 * t] : 0;
  int c1 = (2 * t + 1 < NBUK) ? bucketCount[2 * t + 1] : 0;
  ssc[t] = c0 + c1;
  __syncthreads();
  for (int off = 1; off < 512; off <<= 1) {
    int v = (t >= off) ? ssc[t - off] : 0;
    __syncthreads();
    ssc[t] += v;
    __syncthreads();
  }
  int base = ssc[t] - (c0 + c1);   // exclusive
  if (2 * t < NBUK)     { bucketStart[2 * t] = base;          cursor[2 * t] = base; }
  if (2 * t + 1 < NBUK) { bucketStart[2 * t + 1] = base + c0; cursor[2 * t + 1] = base + c0; }
  if (t == 511) bucketStart[NBUK] = E;
}

__global__ __launch_bounds__(512) void bin_scatter(const int* __restrict__ src,
                                                   const int* __restrict__ dst,
                                                   int* __restrict__ cursor,
                                                   unsigned* __restrict__ pairs,
                                                   int E, int NBUK) {
  __shared__ unsigned ord[TILE];
  __shared__ int hist[MAXBUK], scanS[MAXBUK], gbase[MAXBUK], rank[MAXBUK];
  __shared__ int ssc[512];
  int t = threadIdx.x;
  int tb = blockIdx.x * TILE;
  int nT = min(TILE, E - tb);
  for (int i = t; i < NBUK; i += 512) { hist[i] = 0; rank[i] = 0; }
  __syncthreads();
  for (int i = t; i < nT; i += 512) atomicAdd(&hist[dst[tb + i] >> 7], 1);
  __syncthreads();
  int c0 = (2 * t < NBUK) ? hist[2 * t] : 0;
  int c1 = (2 * t + 1 < NBUK) ? hist[2 * t + 1] : 0;
  ssc[t] = c0 + c1;
  __syncthreads();
  for (int off = 1; off < 512; off <<= 1) {
    int v = (t >= off) ? ssc[t - off] : 0;
    __syncthreads();
    ssc[t] += v;
    __syncthreads();
  }
  int bse = ssc[t] - (c0 + c1);
  if (2 * t < NBUK) scanS[2 * t] = bse;
  if (2 * t + 1 < NBUK) scanS[2 * t + 1] = bse + c0;
  __syncthreads();
  for (int i = t; i < NBUK; i += 512) {
    int c = hist[i];
    if (c) gbase[i] = atomicAdd(&cursor[i], c);
  }
  __syncthreads();
  for (int i = t; i < nT; i += 512) {
    int d = dst[tb + i], s = src[tb + i];
    int b = d >> 7;
    int pos = scanS[b] + atomicAdd(&rank[b], 1);
    ord[pos] = (unsigned)s | ((unsigned)(d & 127) << 17);
  }
  __syncthreads();
  // coalesced flush: wave per bucket round-robin
  int wid = t >> 6, lane = t & 63;
  for (int b = wid; b < NBUK; b += 8) {
    int c = hist[b];
    if (!c) continue;
    int gb = gbase[b], sb = scanS[b];
    for (int j = lane; j < c; j += 64) pairs[gb + j] = ord[sb + j];
  }
}

// per-bucket counting sort -> per-node CSR (coalesced writes) + counts/rowStart/dis
__global__ __launch_bounds__(256) void csr_from_pairs(const unsigned* __restrict__ pairs,
                                                      const int* __restrict__ bucketStart,
                                                      int* __restrict__ csrSrc,
                                                      int* __restrict__ counts,
                                                      int* __restrict__ rowStart,
                                                      float* __restrict__ dis, int N) {
  __shared__ int hist[128], excl[128], rank[128];
  __shared__ int ordS[BCAP];
  int b = blockIdx.x, t = threadIdx.x;
  int base = b << 7;
  int e0 = bucketStart[b], e1 = bucketStart[b + 1];
  int cnt = e1 - e0;
  if (t < 128) { hist[t] = 0; rank[t] = 0; }
  __syncthreads();
  for (int e = e0 + t; e < e1; e += 256) atomicAdd(&hist[pairs[e] >> 17], 1);
  __syncthreads();
  if (t < 128) excl[t] = hist[t];
  __syncthreads();
  for (int off = 1; off < 128; off <<= 1) {
    int v = (t < 128 && t >= off) ? excl[t - off] : 0;
    __syncthreads();
    if (t < 128) excl[t] += v;
    __syncthreads();
  }
  if (t < 128) excl[t] -= hist[t];   // exclusive
  __syncthreads();
  if (t < 128 && base + t < N) {
    int c = hist[t];
    counts[base + t] = c;
    rowStart[base + t] = e0 + excl[t];
    dis[base + t] = rsqrtf((float)(c + 1));
  }
  if (cnt <= BCAP) {
    for (int e = e0 + t; e < e1; e += 256) {
      unsigned p = pairs[e];
      int dl = p >> 17;
      int pos = excl[dl] + atomicAdd(&rank[dl], 1);
      ordS[pos] = (int)(p & 0x1FFFF);
    }
    __syncthreads();
    for (int j = t; j < cnt; j += 256) csrSrc[e0 + j] = ordS[j];
  } else {  // fallback
    for (int e = e0 + t; e < e1; e += 256) {
      unsigned p = pairs[e];
      int dl = p >> 17;
      int pos = excl[dl] + atomicAdd(&rank[dl], 1);
      csrSrc[e0 + pos] = (int)(p & 0x1FFFF);
    }
  }
}

// ---------------- W prep: fp32 -> W^T bf16, XOR-swizzled in k ----------------
// element (n,k) stored at n*128 + (k ^ ((n&15)<<3)) -> gemm stages LINEARLY into LDS
__global__ __launch_bounds__(256) void wprep(const float* __restrict__ W1,
                                             const float* __restrict__ W2,
                                             const float* __restrict__ W3,
                                             unsigned short* __restrict__ W1s,
                                             unsigned short* __restrict__ W2s,
                                             unsigned short* __restrict__ W3s) {
  int t = threadIdx.x;
  if (blockIdx.x < 2) {
    const float* W = blockIdx.x ? W2 : W1;
    unsigned short* Ws = blockIdx.x ? W2s : W1s;
    for (int idx = t; idx < 128 * 128; idx += 256) {
      int n = idx >> 7, k = idx & 127;
      Ws[n * 128 + (k ^ ((n & 15) << 3))] = f2bf(W[k * 128 + n]);
    }
  } else {   // W3: [128][40] -> [48][128] padded
    for (int idx = t; idx < 48 * 128; idx += 256) {
      int n = idx >> 7, k = idx & 127;
      float v = (n < OUTC) ? W3[k * OUTC + n] : 0.f;
      W3s[n * 128 + (k ^ ((n & 15) << 3))] = f2bf(v);
    }
  }
}

// ---------------- MFMA GEMM: [N,128] x [128,128] -> bf16 ----------------
// MODE 0: A fp32, no BN (layer 1). MODE 1: A bf16, fused BN+ReLU (layer 2).
template<int MODE>
__global__ __launch_bounds__(256) void gemm128m(const void* __restrict__ Ain,
                                                const unsigned short* __restrict__ Wsz,
                                                const float* __restrict__ bnsc,
                                                const float* __restrict__ bnsh,
                                                unsigned short* __restrict__ Cbf, int N) {
  __shared__ unsigned short Asw[64 * 128];    // 16 KB, XOR-swizzled
  __shared__ unsigned short Wsw[128 * 128];   // 32 KB, pre-swizzled (linear copy)
  __shared__ float scs[128], shs[128];
  int t = threadIdx.x;
  int rowBase = blockIdx.x * 64;

  if (MODE == 1 && t < 128) { scs[t] = bnsc[t]; shs[t] = bnsh[t]; }
  __syncthreads();

  // stage W: linear coalesced copy (swizzle pre-applied in global)
  {
    const float4* wg = (const float4*)Wsz;
    float4* wl = (float4*)Wsw;
    #pragma unroll
    for (int i = 0; i < 8; ++i) wl[t + 256 * i] = wg[t + 256 * i];
  }
  // stage A, swizzled ds_write_b128
  {
    int r = t >> 2;                // 0..63
    int kc = (t & 3) << 5;         // 0,32,64,96
    int gr = rowBase + r;
    #pragma unroll
    for (int j = 0; j < 4; ++j) {
      int k0 = kc + j * 8;
      float v[8];
      if (gr < N) {
        if (MODE == 0) {
          const float* arow = (const float*)Ain + (size_t)gr * 128 + k0;
          float4 a = *(const float4*)arow;
          float4 b = *(const float4*)(arow + 4);
          v[0] = a.x; v[1] = a.y; v[2] = a.z; v[3] = a.w;
          v[4] = b.x; v[5] = b.y; v[6] = b.z; v[7] = b.w;
        } else {
          const unsigned short* arow = (const unsigned short*)Ain + (size_t)gr * 128 + k0;
          bf16x8 raw = *(const bf16x8*)arow;
          #pragma unroll
          for (int i = 0; i < 8; ++i)
            v[i] = fmaxf(bf2f((unsigned short)raw[i]) * scs[k0 + i] + shs[k0 + i], 0.f);
        }
      } else {
        #pragma unroll
        for (int i = 0; i < 8; ++i) v[i] = 0.f;
      }
      bf16x8 sv;
      #pragma unroll
      for (int i = 0; i < 8; ++i) sv[i] = (short)f2bf(v[i]);
      *(bf16x8*)&Asw[r * 128 + (k0 ^ ((r & 15) << 3))] = sv;
    }
  }
  __syncthreads();

  int w = t >> 6, l = t & 63;
  int lr = l & 15;
  int lk = (l >> 4) << 3;
  f32x4 acc[8];
  #pragma unroll
  for (int nt = 0; nt < 8; ++nt) acc[nt] = (f32x4){0.f, 0.f, 0.f, 0.f};

  #pragma unroll
  for (int kt = 0; kt < 128; kt += 32) {
    int kx = (kt + lk) ^ (lr << 3);
    bf16x8 af = *(const bf16x8*)&Asw[(w * 16 + lr) * 128 + kx];
    #pragma unroll
    for (int nt = 0; nt < 8; ++nt) {
      bf16x8 bfv = *(const bf16x8*)&Wsw[(nt * 16 + lr) * 128 + kx];
      acc[nt] = __builtin_amdgcn_mfma_f32_16x16x32_bf16(af, bfv, acc[nt], 0, 0, 0);
    }
  }

  // D[m][n]: m = (l>>4)*4 + reg, n = nt*16 + lr
  int m0 = rowBase + w * 16 + ((l >> 4) << 2);
  #pragma unroll
  for (int i = 0; i < 4; ++i) {
    int gm = m0 + i;
    if (gm < N) {
      unsigned short* cr = Cbf + (size_t)gm * 128 + lr;
      #pragma unroll
      for (int nt = 0; nt < 8; ++nt) cr[nt * 16] = f2bf(acc[nt][i]);
    }
  }
}

// ---------------- MFMA GEMM: [N,128] x [128,40] with fused BN+ReLU; writes fp32 h ----------------
__global__ __launch_bounds__(256) void gemm40m(const unsigned short* __restrict__ Apre,
                                               const unsigned short* __restrict__ W3sz,
                                               const float* __restrict__ bnsc,
                                               const float* __restrict__ bnsh,
                                               float* __restrict__ hOut,
                                               unsigned short* __restrict__ Cbf, int N) {
  __shared__ unsigned short Asw[64 * 128];   // 16 KB
  __shared__ unsigned short Wsw[48 * 128];   // 12 KB
  __shared__ float scs[128], shs[128];
  int t = threadIdx.x;
  int rowBase = blockIdx.x * 64;
  if (t < 128) { scs[t] = bnsc[t]; shs[t] = bnsh[t]; }
  __syncthreads();
  // stage W3 (48*128*2 B = 768 float4)
  {
    const float4* wg = (const float4*)W3sz;
    float4* wl = (float4*)Wsw;
    #pragma unroll
    for (int i = 0; i < 3; ++i) wl[t + 256 * i] = wg[t + 256 * i];
  }
  // stage A with BN+ReLU; write post-BN h (fp32) — this IS output 2
  {
    int r = t >> 2;
    int kc = (t & 3) << 5;
    int gr = rowBase + r;
    const unsigned short* arow = Apre + (size_t)gr * 128 + kc;
    float* hrow = hOut + (size_t)gr * 128 + kc;
    #pragma unroll
    for (int j = 0; j < 4; ++j) {
      int k0 = kc + j * 8;
      float v[8];
      if (gr < N) {
        bf16x8 raw = *(const bf16x8*)(arow + j * 8);
        #pragma unroll
        for (int i = 0; i < 8; ++i)
          v[i] = fmaxf(bf2f((unsigned short)raw[i]) * scs[k0 + i] + shs[k0 + i], 0.f);
        float4 h0 = make_float4(v[0], v[1], v[2], v[3]);
        float4 h1 = make_float4(v[4], v[5], v[6], v[7]);
        *(float4*)(hrow + j * 8) = h0;
        *(float4*)(hrow + j * 8 + 4) = h1;
      } else {
        #pragma unroll
        for (int i = 0; i < 8; ++i) v[i] = 0.f;
      }
      bf16x8 sv;
      #pragma unroll
      for (int i = 0; i < 8; ++i) sv[i] = (short)f2bf(v[i]);
      *(bf16x8*)&Asw[r * 128 + (k0 ^ ((r & 15) << 3))] = sv;
    }
  }
  __syncthreads();
  int w = t >> 6, l = t & 63;
  int lr = l & 15, lk = (l >> 4) << 3;
  f32x4 acc[3];
  #pragma unroll
  for (int nt = 0; nt < 3; ++nt) acc[nt] = (f32x4){0.f, 0.f, 0.f, 0.f};
  #pragma unroll
  for (int kt = 0; kt < 128; kt += 32) {
    int kx = (kt + lk) ^ (lr << 3);
    bf16x8 af = *(const bf16x8*)&Asw[(w * 16 + lr) * 128 + kx];
    #pragma unroll
    for (int nt = 0; nt < 3; ++nt) {
      bf16x8 bfv = *(const bf16x8*)&Wsw[(nt * 16 + lr) * 128 + kx];
      acc[nt] = __builtin_amdgcn_mfma_f32_16x16x32_bf16(af, bfv, acc[nt], 0, 0, 0);
    }
  }
  int m0 = rowBase + w * 16 + ((l >> 4) << 2);
  #pragma unroll
  for (int i = 0; i < 4; ++i) {
    int gm = m0 + i;
    if (gm < N) {
      unsigned short* cr = Cbf + (size_t)gm * OUTC;
      #pragma unroll
      for (int nt = 0; nt < 3; ++nt) {
        int col = nt * 16 + lr;
        if (col < OUTC) cr[col] = f2bf(acc[nt][i]);
      }
    }
  }
}

// ---------------- aggregation (128 ch, bf16 src): 32 threads/node, bf16 out ----------------
__global__ __launch_bounds__(256) void agg128(const unsigned short* __restrict__ hb,
                                              const float* __restrict__ dis,
                                              const int* __restrict__ rowStart,
                                              const int* __restrict__ counts,
                                              const int* __restrict__ csrSrc,
                                              const float* __restrict__ bias,
                                              unsigned short* __restrict__ outB, int N) {
  int g = threadIdx.x >> 5;
  int q = threadIdx.x & 31;          // owns channels 4q..4q+3
  int i = blockIdx.x * 8 + g;
  if (i >= N) return;
  const ushort4* base = (const ushort4*)hb;  // row = 32 ushort4
  float di = dis[i];
  float wself = di * di;
  ushort4 sv = base[(size_t)i * 32 + q];
  float4 acc;
  acc.x = bf2f(sv.x) * wself; acc.y = bf2f(sv.y) * wself;
  acc.z = bf2f(sv.z) * wself; acc.w = bf2f(sv.w) * wself;
  int s0 = rowStart[i];
  int cnt = counts[i];
  int e = 0;
  for (; e + 3 < cnt; e += 4) {
    int sA = csrSrc[s0 + e],     sB = csrSrc[s0 + e + 1];
    int sC = csrSrc[s0 + e + 2], sD = csrSrc[s0 + e + 3];
    float wA = dis[sA] * di, wB = dis[sB] * di;
    float wC = dis[sC] * di, wD = dis[sD] * di;
    ushort4 vA = base[(size_t)sA * 32 + q];
    ushort4 vB = base[(size_t)sB * 32 + q];
    ushort4 vC = base[(size_t)sC * 32 + q];
    ushort4 vD = base[(size_t)sD * 32 + q];
    acc.x += bf2f(vA.x) * wA; acc.y += bf2f(vA.y) * wA;
    acc.z += bf2f(vA.z) * wA; acc.w += bf2f(vA.w) * wA;
    acc.x += bf2f(vB.x) * wB; acc.y += bf2f(vB.y) * wB;
    acc.z += bf2f(vB.z) * wB; acc.w += bf2f(vB.w) * wB;
    acc.x += bf2f(vC.x) * wC; acc.y += bf2f(vC.y) * wC;
    acc.z += bf2f(vC.z) * wC; acc.w += bf2f(vC.w) * wC;
    acc.x += bf2f(vD.x) * wD; acc.y += bf2f(vD.y) * wD;
    acc.z += bf2f(vD.z) * wD; acc.w += bf2f(vD.w) * wD;
  }
  for (; e < cnt; ++e) {
    int sA = csrSrc[s0 + e];
    float wA = dis[sA] * di;
    ushort4 vA = base[(size_t)sA * 32 + q];
    acc.x += bf2f(vA.x) * wA; acc.y += bf2f(vA.y) * wA;
    acc.z += bf2f(vA.z) * wA; acc.w += bf2f(vA.w) * wA;
  }
  float4 b = ((const float4*)bias)[q];
  ushort4 o;
  o.x = f2bf(acc.x + b.x); o.y = f2bf(acc.y + b.y);
  o.z = f2bf(acc.z + b.z); o.w = f2bf(acc.w + b.w);
  *(ushort4*)&outB[(size_t)i * 128 + 4 * q] = o;
}

// ---------------- BN stats stage 1: per-block partials, no atomics ----------------
// 256 blocks; block owns contiguous row span; partial[b][0..127]=sum, [128..255]=sumsq
__global__ __launch_bounds__(256) void bn_part(const unsigned short* __restrict__ h,
                                               float* __restrict__ partial, int N) {
  int t = threadIdx.x;
  int q = t & 15;     // channel octet: ch 8q..8q+7
  int rg = t >> 4;    // 0..15
  int rowsPer = (N + STATB - 1) / STATB;
  int r0 = blockIdx.x * rowsPer;
  int r1 = min(r0 + rowsPer, N);
  float s[8], s2[8];
  #pragma unroll
  for (int k = 0; k < 8; ++k) { s[k] = 0.f; s2[k] = 0.f; }
  for (int r = r0 + rg; r < r1; r += 16) {
    bf16x8 v = *(const bf16x8*)&h[(size_t)r * 128 + q * 8];
    #pragma unroll
    for (int k = 0; k < 8; ++k) {
      float f = bf2f((unsigned short)v[k]);
      s[k] += f; s2[k] += f * f;
    }
  }
  // wave reduce: lanes {l, l^16, l^32, l^48} share the same q
  #pragma unroll
  for (int k = 0; k < 8; ++k) {
    s[k]  += __shfl_xor(s[k], 16);
    s[k]  += __shfl_xor(s[k], 32);
    s2[k] += __shfl_xor(s2[k], 16);
    s2[k] += __shfl_xor(s2[k], 32);
  }
  __shared__ float sm[4][16][16];   // [wave][q][sum0..7, sq0..7]
  int w = t >> 6, l = t & 63;
  if (l < 16) {
    #pragma unroll
    for (int k = 0; k < 8; ++k) { sm[w][l][k] = s[k]; sm[w][l][8 + k] = s2[k]; }
  }
  __syncthreads();
  int ch = t & 127, part = t >> 7;
  float v = 0.f;
  #pragma unroll
  for (int w2 = 0; w2 < 4; ++w2) v += sm[w2][ch >> 3][part * 8 + (ch & 7)];
  partial[blockIdx.x * 256 + t] = v;   // coalesced, non-atomic
}

// ---------------- BN stats stage 2 + scale/shift ----------------
__global__ __launch_bounds__(256) void bn_scale2(const float* __restrict__ partial,
                                                 float* __restrict__ outc,  // [0..128)=sc, [128..256)=sh
                                                 const float* __restrict__ g,
                                                 const float* __restrict__ be, float invN) {
  __shared__ float red[256];
  int t = threadIdx.x;
  float s = 0.f;
  const float* p = partial + t;
  #pragma unroll 8
  for (int b = 0; b < STATB; ++b) s += p[(size_t)b * 256];
  red[t] = s;
  __syncthreads();
  if (t < 128) {
    float mean = red[t] * invN;
    float var = red[128 + t] * invN - mean * mean;
    float sc = g[t] * rsqrtf(var + BN_EPS);
    outc[t] = sc;
    outc[128 + t] = be[t] - mean * sc;
  }
}

// ---------------- layer-3 aggregation + bias + softmax (16 lanes/node, bf16 source) ----------------
__global__ __launch_bounds__(256) void agg40_softmax(const unsigned short* __restrict__ hb,
                                                     const float* __restrict__ dis,
                                                     const int* __restrict__ rowStart,
                                                     const int* __restrict__ counts,
                                                     const int* __restrict__ csrSrc,
                                                     const float* __restrict__ b3,
                                                     float* __restrict__ out, int N) {
  int l = threadIdx.x & 15;      // lanes 0..9 active (10*4 = 40 ch)
  int g = threadIdx.x >> 4;      // 16 nodes/block
  int i = blockIdx.x * 16 + g;
  if (i >= N) return;
  bool act = l < 10;
  float di = dis[i];
  float4 acc = make_float4(0.f, 0.f, 0.f, 0.f);
  if (act) {
    ushort4 sv = *(const ushort4*)&hb[(size_t)i * OUTC + l * 4];
    float w = di * di;
    acc.x = bf2f(sv.x) * w; acc.y = bf2f(sv.y) * w;
    acc.z = bf2f(sv.z) * w; acc.w = bf2f(sv.w) * w;
  }
  int s0 = rowStart[i];
  int cnt = counts[i];
  int e = 0;
  for (; e + 1 < cnt; e += 2) {
    int sA = csrSrc[s0 + e], sB = csrSrc[s0 + e + 1];
    float wA = dis[sA] * di, wB = dis[sB] * di;
    if (act) {
      ushort4 vA = *(const ushort4*)&hb[(size_t)sA * OUTC + l * 4];
      ushort4 vB = *(const ushort4*)&hb[(size_t)sB * OUTC + l * 4];
      acc.x += bf2f(vA.x) * wA; acc.y += bf2f(vA.y) * wA;
      acc.z += bf2f(vA.z) * wA; acc.w += bf2f(vA.w) * wA;
      acc.x += bf2f(vB.x) * wB; acc.y += bf2f(vB.y) * wB;
      acc.z += bf2f(vB.z) * wB; acc.w += bf2f(vB.w) * wB;
    }
  }
  if (e < cnt) {
    int sA = csrSrc[s0 + e];
    float wA = dis[sA] * di;
    if (act) {
      ushort4 vA = *(const ushort4*)&hb[(size_t)sA * OUTC + l * 4];
      acc.x += bf2f(vA.x) * wA; acc.y += bf2f(vA.y) * wA;
      acc.z += bf2f(vA.z) * wA; acc.w += bf2f(vA.w) * wA;
    }
  }
  if (act) {
    float4 b = ((const float4*)b3)[l];
    acc.x += b.x; acc.y += b.y; acc.z += b.z; acc.w += b.w;
  }
  float m = act ? fmaxf(fmaxf(acc.x, acc.y), fmaxf(acc.z, acc.w)) : -1e30f;
  #pragma unroll
  for (int off = 8; off; off >>= 1) m = fmaxf(m, __shfl_xor(m, off, 16));
  float4 ex = make_float4(0.f, 0.f, 0.f, 0.f);
  float lsum = 0.f;
  if (act) {
    ex.x = __expf(acc.x - m); ex.y = __expf(acc.y - m);
    ex.z = __expf(acc.z - m); ex.w = __expf(acc.w - m);
    lsum = ex.x + ex.y + ex.z + ex.w;
  }
  #pragma unroll
  for (int off = 8; off; off >>= 1) lsum += __shfl_xor(lsum, off, 16);
  if (act) {
    float inv = 1.0f / lsum;
    float4 o;
    o.x = ex.x * inv; o.y = ex.y * inv; o.z = ex.z * inv; o.w = ex.w * inv;
    *(float4*)&out[(size_t)i * OUTC + l * 4] = o;
  }
}

// ---------------- launcher ----------------
extern "C" void kernel_launch(void* const* d_in, const int* in_sizes, int n_in,
                              void* d_out, int out_size, void* d_ws, size_t ws_size,
                              hipStream_t stream) {
  const float* x   = (const float*)d_in[0];
  const int*   ei  = (const int*)d_in[1];
  const float* W1  = (const float*)d_in[2];
  const float* b1  = (const float*)d_in[3];
  const float* g1  = (const float*)d_in[4];
  const float* be1 = (const float*)d_in[5];
  const float* W2  = (const float*)d_in[6];
  const float* b2  = (const float*)d_in[7];
  const float* g2  = (const float*)d_in[8];
  const float* be2 = (const float*)d_in[9];
  const float* W3  = (const float*)d_in[10];
  const float* b3  = (const float*)d_in[11];

  const int N = in_sizes[0] / HIDC;
  const int E = in_sizes[1] / 2;
  const int NBUK = (N + 127) >> 7;
  const int* srcI = ei;
  const int* dstI = ei + E;

  float* outSoft = (float*)d_out;                       // [N,40]
  float* outH    = (float*)d_out + (size_t)N * OUTC;    // [N,128] final h (written by gemm40m)

  char* ws = (char*)d_ws;
  size_t off = 0;
  auto alloc = [&](size_t bytes) -> char* {
    char* p = ws + off;
    off += (bytes + 255) & ~(size_t)255;
    return p;
  };
  unsigned short* bufAbf  = (unsigned short*)alloc((size_t)N * HIDC * 2);  // gemm out (bf16)
  unsigned short* hPre    = (unsigned short*)alloc((size_t)N * HIDC * 2);  // preBN agg (bf16)
  unsigned short* buf40bf = (unsigned short*)alloc((size_t)N * OUTC * 2);  // gemm40 out (bf16)
  unsigned short* W1sz    = (unsigned short*)alloc(128 * 128 * 2);
  unsigned short* W2sz    = (unsigned short*)alloc(128 * 128 * 2);
  unsigned short* W3sz    = (unsigned short*)alloc(48 * 128 * 2);
  float*    dis         = (float*)alloc((size_t)N * 4);
  float*    partial     = (float*)alloc((size_t)STATB * 256 * 4);  // bn partials
  float*    bnc         = (float*)alloc(512 * 4);                  // sc/sh for BN1, BN2
  int*      bucketCount = (int*)alloc((size_t)MAXBUK * 4);
  int*      bucketStart = (int*)alloc((size_t)(MAXBUK + 1) * 4);
  int*      cursor      = (int*)alloc((size_t)MAXBUK * 4);
  int*      counts      = (int*)alloc((size_t)N * 4);
  int*      rowStart    = (int*)alloc((size_t)N * 4);
  unsigned* pairs       = (unsigned*)alloc((size_t)E * 4);
  int*      csrSrc      = (int*)alloc((size_t)E * 4);
  (void)ws_size; (void)n_in;

  hipMemsetAsync(bucketCount, 0, (size_t)MAXBUK * 4, stream);

  // bucket-sorted CSR build (all writes coalesced) + W prep
  wprep<<<3, 256, 0, stream>>>(W1, W2, W3, W1sz, W2sz, W3sz);
  bin_hist<<<512, 256, 0, stream>>>(dstI, bucketCount, E, NBUK);
  scan_buckets<<<1, 512, 0, stream>>>(bucketCount, bucketStart, cursor, NBUK, E);
  bin_scatter<<<(E + TILE - 1) / TILE, 512, 0, stream>>>(srcI, dstI, cursor, pairs, E, NBUK);
  csr_from_pairs<<<NBUK, 256, 0, stream>>>(pairs, bucketStart, csrSrc, counts, rowStart,
                                           dis, N);

  const float invN = 1.0f / (float)N;

  // ---- Layer 1: x -> bufAbf -> hPre (bf16 preBN) ----
  gemm128m<0><<<(N + 63) / 64, 256, 0, stream>>>(x, W1sz, nullptr, nullptr, bufAbf, N);
  agg128<<<(N + 7) / 8, 256, 0, stream>>>(bufAbf, dis, rowStart, counts, csrSrc,
                                          b1, hPre, N);
  bn_part<<<STATB, 256, 0, stream>>>(hPre, partial, N);
  bn_scale2<<<1, 256, 0, stream>>>(partial, bnc, g1, be1, invN);

  // ---- Layer 2: BN1+ReLU fused into gemm A-load (bf16 A) ----
  gemm128m<1><<<(N + 63) / 64, 256, 0, stream>>>(hPre, W2sz, bnc, bnc + 128, bufAbf, N);
  agg128<<<(N + 7) / 8, 256, 0, stream>>>(bufAbf, dis, rowStart, counts, csrSrc,
                                          b2, hPre, N);
  bn_part<<<STATB, 256, 0, stream>>>(hPre, partial, N);
  bn_scale2<<<1, 256, 0, stream>>>(partial, bnc + 256, g2, be2, invN);

  // ---- Layer 3: BN2+ReLU fused into gemm40m (writes fp32 h to outH) ----
  gemm40m<<<(N + 63) / 64, 256, 0, stream>>>(hPre, W3sz, bnc + 256, bnc + 384,
                                             outH, buf40bf, N);
  agg40_softmax<<<(N + 15) / 16, 256, 0, stream>>>(buf40bf, dis, rowStart, counts,
                                                   csrSrc, b3, outSoft, N);
}